// Round 8
// baseline (2627.031 us; speedup 1.0000x reference)
//
#include <hip/hip_runtime.h>
#include <math.h>

#define HZN 10
#define NBLK 256

__device__ __forceinline__ float sigm(float x) { return 1.f / (1.f + expf(-x)); }
__device__ __forceinline__ float gelu_f(float x) { return 0.5f * x * (1.f + erff(x * 0.70710678118654752f)); }

__device__ __forceinline__ float cLd(const float* p) {
  return __hip_atomic_load(p, __ATOMIC_RELAXED, __HIP_MEMORY_SCOPE_AGENT);
}
__device__ __forceinline__ void cSt(float* p, float v) {
  __hip_atomic_store(p, v, __ATOMIC_RELAXED, __HIP_MEMORY_SCOPE_AGENT);
}
__device__ __forceinline__ unsigned cLdU(const unsigned* p) {
  return __hip_atomic_load(p, __ATOMIC_RELAXED, __HIP_MEMORY_SCOPE_AGENT);
}
__device__ __forceinline__ void cStU(unsigned* p, unsigned v) {
  __hip_atomic_store(p, v, __ATOMIC_RELAXED, __HIP_MEMORY_SCOPE_AGENT);
}
__device__ __forceinline__ void vfence() {
  asm volatile("s_waitcnt vmcnt(0)" ::: "memory");
}

__device__ __forceinline__ float blo(unsigned u) { return __uint_as_float(u << 16); }
__device__ __forceinline__ float bhi(unsigned u) { return __uint_as_float(u & 0xffff0000u); }
__device__ __forceinline__ unsigned bfu(float x) {
  unsigned u = __float_as_uint(x);
  return (u + 0x7fffu + ((u >> 16) & 1u)) >> 16;
}
__device__ __forceinline__ unsigned packbf(float a, float b) {
  return bfu(a) | (bfu(b) << 16);
}

// detector barrier (rounds 2-5,7 proven)
__device__ __forceinline__ void gbar(unsigned* flags, unsigned* gen, int bid, int tid, unsigned& bgen) {
  ++bgen;
  vfence();
  __syncthreads();
  if (bid == 0) {
    if (tid > 0 && tid < NBLK) {
      while (cLdU(&flags[tid]) < bgen) __builtin_amdgcn_s_sleep(1);
    }
    __syncthreads();
    if (tid == 0) cStU(gen, bgen);
  } else {
    if (tid == 0) {
      cStU(&flags[bid], bgen);
      while (cLdU(gen) < bgen) __builtin_amdgcn_s_sleep(1);
    }
    __syncthreads();
  }
}

// ---------------------------------------------------------------- setup
__global__ void setup_kernel(const int* __restrict__ ei, const float* __restrict__ ew,
                             int* __restrict__ cptr, int* __restrict__ csrc, float* __restrict__ cnorm) {
  __shared__ float deg[100];
  __shared__ float dinv[100];
  __shared__ int cnt[100];
  __shared__ int pos[100];
  __shared__ int ptr[101];
  const int t = threadIdx.x;
  if (t < 100) { deg[t] = 0.f; cnt[t] = 0; }
  __syncthreads();
  for (int e = t; e < 2000; e += 256) {
    int c = ei[2000 + e];
    atomicAdd(&deg[c], ew[e]);
    atomicAdd(&cnt[c], 1);
  }
  __syncthreads();
  if (t < 100) dinv[t] = (deg[t] > 0.f) ? 1.f / sqrtf(fmaxf(deg[t], 1e-12f)) : 0.f;
  if (t == 0) {
    ptr[0] = 0;
    for (int n = 0; n < 100; ++n) ptr[n + 1] = ptr[n] + cnt[n];
  }
  __syncthreads();
  if (t < 100) pos[t] = ptr[t];
  if (t < 101) cptr[t] = ptr[t];
  __syncthreads();
  for (int e = t; e < 2000; e += 256) {
    int r = ei[e], c = ei[2000 + e];
    int p = atomicAdd(&pos[c], 1);
    csrc[p] = r;
    cnorm[p] = dinv[r] * ew[e] * dinv[c];
  }
}

// ------------------- weight packing: row-major bf16 pairs [rows][(Ka+Kb)/2]
__global__ void pack_rows(const float* __restrict__ A, const float* __restrict__ B,
                          int Ka, int Kb, int rows, unsigned* __restrict__ out) {
  int K2 = (Ka + Kb) >> 1;
  long idx = (long)blockIdx.x * 256 + threadIdx.x;
  if (idx >= (long)rows * K2) return;
  int row = idx / K2, q = idx - (long)row * K2;
  int j0 = 2 * q;
  float a = (j0 < Ka) ? A[(long)row * Ka + j0] : B[(long)row * Kb + (j0 - Ka)];
  float b = (j0 + 1 < Ka) ? A[(long)row * Ka + j0 + 1] : B[(long)row * Kb + (j0 + 1 - Ka)];
  out[idx] = packbf(a, b);
}

// ---------------------------------------------------------------- TGConv -> XS[T][B][3200]
__global__ void xs_kernel(const float* __restrict__ win,
                          const int* __restrict__ cptr, const int* __restrict__ csrc,
                          const float* __restrict__ cnorm,
                          const float* __restrict__ tgw, const float* __restrict__ tgv,
                          const float* __restrict__ tgb, const float* __restrict__ Wemb,
                          float* __restrict__ XS) {
  const int g = blockIdx.x * 256 + threadIdx.x;
  if (g >= 102400) return;
  const int n2 = g % 100;
  const int base = g - n2;
  float s = 0.f;
  const int p0 = cptr[n2], p1 = cptr[n2 + 1];
  for (int p = p0; p < p1; ++p) s += cnorm[p] * win[base + csrc[p]];
  const float x = win[g];
  const int t = g % 64;
  const int bb = g / 6400;
  const int n = (g / 64) % 100;
  float* dst = XS + (size_t)(t * 16 + bb) * 3200 + n * 32;
  for (int c = 0; c < 32; ++c) {
    float v = s * tgw[c] + x * tgv[c] + tgb[c];
    dst[c] = gelu_f(v) + Wemb[n * 32 + c];
  }
}

// ---------------------------------------------------------------- G0 = XS @ Wih0^T + biases
__global__ __launch_bounds__(256) void g0_gemm(const float* __restrict__ XS, const float* __restrict__ W,
                                               const float* __restrict__ b1, const float* __restrict__ b2,
                                               float* __restrict__ G0) {
  __shared__ float As[16][68];
  __shared__ float Bs[16][68];
  const int tid = threadIdx.x;
  const int m0 = blockIdx.y * 64, n0 = blockIdx.x * 64;
  const int tx = tid & 15, ty = tid >> 4;
  const int lr = tid >> 2, lk = (tid & 3) * 4;
  float acc[4][4] = {};
  for (int k0 = 0; k0 < 3200; k0 += 16) {
    float4 av = *(const float4*)&XS[(size_t)(m0 + lr) * 3200 + k0 + lk];
    float4 bv = *(const float4*)&W[(size_t)(n0 + lr) * 3200 + k0 + lk];
    As[lk + 0][lr] = av.x; As[lk + 1][lr] = av.y; As[lk + 2][lr] = av.z; As[lk + 3][lr] = av.w;
    Bs[lk + 0][lr] = bv.x; Bs[lk + 1][lr] = bv.y; Bs[lk + 2][lr] = bv.z; Bs[lk + 3][lr] = bv.w;
    __syncthreads();
#pragma unroll
    for (int kk = 0; kk < 16; ++kk) {
      float4 a = *(const float4*)&As[kk][ty * 4];
      float4 b = *(const float4*)&Bs[kk][tx * 4];
      acc[0][0] += a.x * b.x; acc[0][1] += a.x * b.y; acc[0][2] += a.x * b.z; acc[0][3] += a.x * b.w;
      acc[1][0] += a.y * b.x; acc[1][1] += a.y * b.y; acc[1][2] += a.y * b.z; acc[1][3] += a.y * b.w;
      acc[2][0] += a.z * b.x; acc[2][1] += a.z * b.y; acc[2][2] += a.z * b.z; acc[2][3] += a.z * b.w;
      acc[3][0] += a.w * b.x; acc[3][1] += a.w * b.y; acc[3][2] += a.w * b.z; acc[3][3] += a.w * b.w;
    }
    __syncthreads();
  }
#pragma unroll
  for (int i = 0; i < 4; ++i) {
    const int m = m0 + ty * 4 + i;
#pragma unroll
    for (int j = 0; j < 4; ++j) {
      const int nn = n0 + tx * 4 + j;
      G0[(size_t)m * 2048 + nn] = acc[i][j] + b1[nn] + b2[nn];
    }
  }
}

// ---------------------------------------------------------------- scan kernel (R7 structure, unchanged)
struct ScanArgs {
  const float* G0;
  const unsigned* W0p;       // [2048][256]
  const unsigned* W1p;       // [2048][512]
  const float* bih1; const float* bhh1;
  float* hs0;     // [64][16][512]
  float* h1ex;    // [2][16][512]  (layer-1 output ping-pong; slot1 = final)
  unsigned* F0;   // [16][8]
  unsigned* F1;   // [16][8]
};

__global__ __launch_bounds__(512, 1) void scan_kernel(ScanArgs A) {
  __shared__ float lds[1280];
  const int tid = threadIdx.x;
  const int bid = blockIdx.x;

  if (bid < 128) {
    const int b = bid >> 3, j = bid & 7;
    const int r = tid >> 1, hf = tid & 1;
    const uint4* wp = (const uint4*)A.W0p + ((size_t)((r >> 6) * 512 + j * 64 + (r & 63))) * 64 + hf * 32;
    float* hl = lds;
    float* gl = lds + 512;
    float c0r = 0.f;
    for (int t = 0; t < 64; ++t) {
      if (t > 0) {
        if (tid < 8) {
          while (cLdU(&A.F0[b * 8 + tid]) < (unsigned)t) __builtin_amdgcn_s_sleep(1);
        }
        __syncthreads();
        hl[tid] = cLd(&A.hs0[((size_t)(t - 1) * 16 + b) * 512 + tid]);
        __syncthreads();
      }
      float acc = 0.f;
      if (t > 0) {
        const float2* h2 = (const float2*)hl + hf * 128;
#pragma unroll 8
        for (int i = 0; i < 32; ++i) {
          uint4 w = wp[i];
          float2 ha = h2[4 * i], hb = h2[4 * i + 1], hc = h2[4 * i + 2], hd = h2[4 * i + 3];
          acc += blo(w.x) * ha.x + bhi(w.x) * ha.y;
          acc += blo(w.y) * hb.x + bhi(w.y) * hb.y;
          acc += blo(w.z) * hc.x + bhi(w.z) * hc.y;
          acc += blo(w.w) * hd.x + bhi(w.w) * hd.y;
        }
      }
      acc += __shfl_xor(acc, 1);
      if (hf == 0) gl[r] = acc;
      __syncthreads();
      if (tid < 64) {
        const float* g0r = A.G0 + ((size_t)t * 16 + b) * 2048 + j * 64;
        float gi = gl[tid] + g0r[tid];
        float gf = gl[64 + tid] + g0r[512 + tid];
        float gg = gl[128 + tid] + g0r[1024 + tid];
        float go = gl[192 + tid] + g0r[1536 + tid];
        c0r = sigm(gf) * c0r + sigm(gi) * tanhf(gg);
        float hn = sigm(go) * tanhf(c0r);
        cSt(&A.hs0[((size_t)t * 16 + b) * 512 + j * 64 + tid], hn);
      }
      vfence();
      __syncthreads();
      if (tid == 0) cStU(&A.F0[b * 8 + j], t + 1);
    }
  } else {
    const int b = (bid - 128) >> 3, j = bid & 7;
    const int r = tid >> 1, hf = tid & 1;
    const int wrow = (r >> 6) * 512 + j * 64 + (r & 63);
    const uint4* wp = (const uint4*)A.W1p + (size_t)wrow * 128 + hf * 64;
    float* hl = lds;
    float* gl = lds + 1024;
    float c1s = 0.f;
    for (int t = 0; t < 64; ++t) {
      if (tid < 8) {
        while (cLdU(&A.F0[b * 8 + tid]) < (unsigned)(t + 1)) __builtin_amdgcn_s_sleep(1);
        if (t > 0) {
          while (cLdU(&A.F1[b * 8 + tid]) < (unsigned)t) __builtin_amdgcn_s_sleep(1);
        }
      }
      __syncthreads();
      hl[tid] = cLd(&A.hs0[((size_t)t * 16 + b) * 512 + tid]);
      hl[512 + tid] = (t > 0) ? cLd(&A.h1ex[(((t - 1) & 1) * 16 + b) * 512 + tid]) : 0.f;
      __syncthreads();
      float acc = 0.f;
      {
        const float2* h2 = (const float2*)hl + hf * 256;
#pragma unroll 8
        for (int i = 0; i < 64; ++i) {
          uint4 w = wp[i];
          float2 ha = h2[4 * i], hb = h2[4 * i + 1], hc = h2[4 * i + 2], hd = h2[4 * i + 3];
          acc += blo(w.x) * ha.x + bhi(w.x) * ha.y;
          acc += blo(w.y) * hb.x + bhi(w.y) * hb.y;
          acc += blo(w.z) * hc.x + bhi(w.z) * hc.y;
          acc += blo(w.w) * hd.x + bhi(w.w) * hd.y;
        }
      }
      acc += __shfl_xor(acc, 1);
      if (hf == 0) gl[r] = acc;
      __syncthreads();
      if (tid < 64) {
        int uu = j * 64 + tid;
        float gi = gl[tid] + A.bih1[uu] + A.bhh1[uu];
        float gf = gl[64 + tid] + A.bih1[512 + uu] + A.bhh1[512 + uu];
        float gg = gl[128 + tid] + A.bih1[1024 + uu] + A.bhh1[1024 + uu];
        float go = gl[192 + tid] + A.bih1[1536 + uu] + A.bhh1[1536 + uu];
        c1s = sigm(gf) * c1s + sigm(gi) * tanhf(gg);
        float hn = sigm(go) * tanhf(c1s);
        cSt(&A.h1ex[((t & 1) * 16 + b) * 512 + uu], hn);
      }
      vfence();
      __syncthreads();
      if (tid == 0) cStU(&A.F1[b * 8 + j], t + 1);
    }
  }
}

// ---------------------------------------------------------------- decoder kernel (even/odd LDS, conflict-free)
struct DecArgs {
  const unsigned* c1Wih2;    // [2048][1600]
  const unsigned* c1Whh2;    // [2048][256]
  const float* c1bih; const float* c1bhh;
  const unsigned* c2W2;      // [2048][512]
  const float* c2bih; const float* c2bhh;
  const float* Wp; const float* bp;
  const float* gw; const float* gv; const float* gb;
  const float* Wemb;
  const int* cptr; const int* csrc; const float* cnorm;
  const float* hs0;   // scan outputs
  const float* h1ex;
  unsigned* h1pk; // [2][16][256]
  unsigned* h2pk; // [2][16][256]
  float* h2f;     // [2][16][512]
  unsigned* bflags; unsigned* gen;
  float* out;
};

// dynamic LDS layout (floats):
//   xeven[8*1600]=12800 @0 | xodd @12800 | h1e[8*256]=2048 @25600 | h1o @27648
//   h2l[8*512]=4096 @29696 | predl[800] @33792 | s2l[800] @34592 | gatel[128] @35392
// total 35520 floats = 142080 B
#define D_XE 0
#define D_XO 12800
#define D_H1E 25600
#define D_H1O 27648
#define D_H2L 29696
#define D_PRED 33792
#define D_S2 34592
#define D_GATE 35392

__global__ __launch_bounds__(512, 1) void dec_kernel(DecArgs A) {
  extern __shared__ float lds[];
  const int tid = threadIdx.x;
  const int bid = blockIdx.x;
  unsigned bgen = 0;

  const int u0 = bid * 2;
  float* xeven = lds + D_XE;
  float* xodd = lds + D_XO;
  float* h1e = lds + D_H1E;
  float* h1o = lds + D_H1O;
  float* h2l = lds + D_H2L;
  float* predl = lds + D_PRED;
  float* s2l = lds + D_S2;
  float* gatel = lds + D_GATE;

  float c1reg[2];
  float c2reg = 0.f;
  if (tid < 16) {
#pragma unroll
    for (int p = 0; p < 2; ++p) {
      int bl = tid >> 1, du = tid & 1;
      c1reg[p] = cLd(&A.hs0[((size_t)63 * 16 + p * 8 + bl) * 512 + u0 + du]);
    }
  }
  if (tid < 32) {
    int bl = tid >> 1, du = tid & 1;
    c2reg = cLd(&A.h1ex[(1 * 16 + bl) * 512 + u0 + du]);
  }

  for (int hz = 0; hz < HZN; ++hz) {
    const int cur = hz & 1, nxt = cur ^ 1;

    // ---- G1: pred + graph conv + cell1, two batch-passes of 8 ----
#pragma unroll
    for (int p = 0; p < 2; ++p) {
      const int B0 = p * 8;
      for (int k = 0; k < 8; ++k) {
        int i = k * 512 + tid;
        int bb = i >> 9, u = i & 511;
        float v = (hz == 0) ? cLd(&A.h1ex[(1 * 16 + B0 + bb) * 512 + u])
                            : cLd(&A.h2f[((size_t)cur * 16 + B0 + bb) * 512 + u]);
        h2l[i] = v;
      }
      for (int k = 0; k < 4; ++k) {
        int i = k * 512 + tid;
        int bb = i >> 8, pp = i & 255;
        float x0, x1;
        if (hz == 0) {
          x0 = cLd(&A.hs0[((size_t)63 * 16 + B0 + bb) * 512 + 2 * pp]);
          x1 = cLd(&A.hs0[((size_t)63 * 16 + B0 + bb) * 512 + 2 * pp + 1]);
        } else {
          unsigned pk = cLdU(&A.h1pk[((size_t)cur * 16 + B0 + bb) * 256 + pp]);
          x0 = blo(pk); x1 = bhi(pk);
        }
        h1e[bb * 256 + pp] = x0;
        h1o[bb * 256 + pp] = x1;
      }
      __syncthreads();
      // pred = h2 @ Wp^T + bp (redundant per block)
      {
        const int g16 = tid >> 4, ln = tid & 15;
        for (int it = 0; it < 4; ++it) {
          const int n2 = it * 32 + g16;
          if (n2 < 100) {
            float w[32];
#pragma unroll
            for (int kk = 0; kk < 32; ++kk) w[kk] = A.Wp[n2 * 512 + kk * 16 + ln];
            for (int bb = 0; bb < 8; ++bb) {
              float a = 0.f;
#pragma unroll
              for (int kk = 0; kk < 32; ++kk) a += w[kk] * h2l[bb * 512 + kk * 16 + ln];
              a += __shfl_xor(a, 1); a += __shfl_xor(a, 2);
              a += __shfl_xor(a, 4); a += __shfl_xor(a, 8);
              if (ln == 0) predl[bb * 100 + n2] = a + A.bp[n2];
            }
          }
        }
      }
      __syncthreads();
      if (bid == 0) {
        for (int i = tid; i < 800; i += 512) {
          int bb = i / 100, n2 = i - bb * 100;
          A.out[((B0 + bb) * 100 + n2) * HZN + hz] = predl[i];
        }
      }
      for (int i = tid; i < 800; i += 512) {
        int bb = i / 100, n2 = i - bb * 100;
        float s2 = 0.f;
        for (int pp = A.cptr[n2]; pp < A.cptr[n2 + 1]; ++pp)
          s2 += A.cnorm[pp] * predl[bb * 100 + A.csrc[pp]];
        s2l[i] = s2;
      }
      __syncthreads();
      // xin -> even/odd split arrays
      for (int k = 0; k < 50; ++k) {
        int i2 = k * 512 + tid;
        int bb = i2 / 3200, rem = i2 - bb * 3200;
        int n2 = rem >> 5, cc = rem & 31;
        float v = s2l[bb * 100 + n2] * A.gw[cc] + predl[bb * 100 + n2] * A.gv[cc] + A.gb[cc];
        float xv = gelu_f(v) + A.Wemb[n2 * 32 + cc];
        if (rem & 1) xodd[bb * 1600 + (rem >> 1)] = xv;
        else         xeven[bb * 1600 + (rem >> 1)] = xv;
      }
      __syncthreads();
      // cell1 gates: stride-1 LDS reads (conflict-free)
      {
        float acc[8] = {};
        const int r_ = tid >> 6, ks = tid & 63;
        const int wrow = (r_ >> 1) * 512 + u0 + (r_ & 1);
        for (int jj = 0; jj < 25; ++jj) {
          int pi = jj * 64 + ks;
          unsigned w = A.c1Wih2[(size_t)wrow * 1600 + pi];
          float wl = blo(w), wh = bhi(w);
#pragma unroll
          for (int bb = 0; bb < 8; ++bb) {
            acc[bb] += wl * xeven[bb * 1600 + pi] + wh * xodd[bb * 1600 + pi];
          }
        }
        for (int jj = 0; jj < 4; ++jj) {
          int pi = jj * 64 + ks;
          unsigned w = A.c1Whh2[wrow * 256 + pi];
          float wl = blo(w), wh = bhi(w);
#pragma unroll
          for (int bb = 0; bb < 8; ++bb) {
            acc[bb] += wl * h1e[bb * 256 + pi] + wh * h1o[bb * 256 + pi];
          }
        }
#pragma unroll
        for (int bb = 0; bb < 8; ++bb) {
          float v = acc[bb];
          v += __shfl_xor(v, 32); v += __shfl_xor(v, 16); v += __shfl_xor(v, 8);
          v += __shfl_xor(v, 4); v += __shfl_xor(v, 2); v += __shfl_xor(v, 1);
          acc[bb] = v;
        }
        if (ks == 0) {
#pragma unroll
          for (int bb = 0; bb < 8; ++bb) gatel[r_ * 8 + bb] = acc[bb];
        }
      }
      __syncthreads();
      if (tid < 16) {
        int bl = tid >> 1, du = tid & 1;
        int uu = u0 + du;
        float gi = gatel[(0 + du) * 8 + bl] + A.c1bih[uu] + A.c1bhh[uu];
        float gf = gatel[(2 + du) * 8 + bl] + A.c1bih[512 + uu] + A.c1bhh[512 + uu];
        float gg = gatel[(4 + du) * 8 + bl] + A.c1bih[1024 + uu] + A.c1bhh[1024 + uu];
        float go = gatel[(6 + du) * 8 + bl] + A.c1bih[1536 + uu] + A.c1bhh[1536 + uu];
        float cn = sigm(gf) * c1reg[p] + sigm(gi) * tanhf(gg);
        float hn = sigm(go) * tanhf(cn);
        c1reg[p] = cn;
        float ho = __shfl(hn, tid ^ 1);
        if (du == 0) cStU(&A.h1pk[((size_t)nxt * 16 + B0 + bl) * 256 + bid], packbf(hn, ho));
      }
      __syncthreads();
    }
    gbar(A.bflags, A.gen, bid, tid, bgen);

    // ---- G2: cell2 ----
    {
      unsigned* h1b = (unsigned*)lds;         // [16][256]
      unsigned* h2b = (unsigned*)lds + 4096;  // [16][256]
      for (int k = 0; k < 8; ++k) {
        int i = k * 512 + tid;
        int bb = i >> 8, pp = i & 255;
        h1b[i] = cLdU(&A.h1pk[((size_t)nxt * 16 + bb) * 256 + pp]);
        unsigned v2;
        if (hz == 0) {
          float x0 = cLd(&A.h1ex[(16 + bb) * 512 + 2 * pp]);
          float x1 = cLd(&A.h1ex[(16 + bb) * 512 + 2 * pp + 1]);
          v2 = packbf(x0, x1);
        } else {
          v2 = cLdU(&A.h2pk[((size_t)cur * 16 + bb) * 256 + pp]);
        }
        h2b[i] = v2;
      }
      __syncthreads();
      float acc[16] = {};
      const int r_ = tid >> 6, ks = tid & 63;
      const int wrow = (r_ >> 1) * 512 + u0 + (r_ & 1);
      for (int jj = 0; jj < 8; ++jj) {
        int pi = jj * 64 + ks;
        unsigned w = A.c2W2[wrow * 512 + pi];
        float wl = blo(w), wh = bhi(w);
        const unsigned* hsrc = (pi < 256) ? h1b : (h2b - 256);
#pragma unroll
        for (int bb = 0; bb < 16; ++bb) {
          unsigned hv = hsrc[bb * 256 + pi];
          acc[bb] += wl * blo(hv) + wh * bhi(hv);
        }
      }
#pragma unroll
      for (int bb = 0; bb < 16; ++bb) {
        float v = acc[bb];
        v += __shfl_xor(v, 32); v += __shfl_xor(v, 16); v += __shfl_xor(v, 8);
        v += __shfl_xor(v, 4); v += __shfl_xor(v, 2); v += __shfl_xor(v, 1);
        acc[bb] = v;
      }
      if (ks == 0) {
#pragma unroll
        for (int bb = 0; bb < 16; ++bb) gatel[r_ * 16 + bb] = acc[bb];
      }
      __syncthreads();
      if (tid < 32) {
        int bl = tid >> 1, du = tid & 1;
        int uu = u0 + du;
        float gi = gatel[(0 + du) * 16 + bl] + A.c2bih[uu] + A.c2bhh[uu];
        float gf = gatel[(2 + du) * 16 + bl] + A.c2bih[512 + uu] + A.c2bhh[512 + uu];
        float gg = gatel[(4 + du) * 16 + bl] + A.c2bih[1024 + uu] + A.c2bhh[1024 + uu];
        float go = gatel[(6 + du) * 16 + bl] + A.c2bih[1536 + uu] + A.c2bhh[1536 + uu];
        float cn = sigm(gf) * c2reg + sigm(gi) * tanhf(gg);
        float hn = sigm(go) * tanhf(cn);
        c2reg = cn;
        cSt(&A.h2f[((size_t)nxt * 16 + bl) * 512 + uu], hn);
        float ho = __shfl(hn, tid ^ 1);
        if (du == 0) cStU(&A.h2pk[((size_t)nxt * 16 + bl) * 256 + bid], packbf(hn, ho));
      }
      __syncthreads();
    }
    gbar(A.bflags, A.gen, bid, tid, bgen);
  }
}

// ---------------------------------------------------------------- launch
extern "C" void kernel_launch(void* const* d_in, const int* in_sizes, int n_in,
                              void* d_out, int out_size, void* d_ws, size_t ws_size,
                              hipStream_t stream) {
  (void)in_sizes; (void)n_in; (void)out_size; (void)ws_size;
  const float* window = (const float*)d_in[0];
  const int* ei = (const int*)d_in[1];
  const float* ew = (const float*)d_in[2];
  const float* Wemb = (const float*)d_in[3];
  const float* tgw = (const float*)d_in[4];
  const float* tgv = (const float*)d_in[5];
  const float* tgb = (const float*)d_in[6];
  const float* gw = (const float*)d_in[7];
  const float* gv = (const float*)d_in[8];
  const float* gb = (const float*)d_in[9];
  const float* Wih0 = (const float*)d_in[10];
  const float* Whh0 = (const float*)d_in[11];
  const float* bih0 = (const float*)d_in[12];
  const float* bhh0 = (const float*)d_in[13];
  const float* Wih1 = (const float*)d_in[14];
  const float* Whh1 = (const float*)d_in[15];
  const float* bih1 = (const float*)d_in[16];
  const float* bhh1 = (const float*)d_in[17];
  const float* c1Wih = (const float*)d_in[18];
  const float* c1Whh = (const float*)d_in[19];
  const float* c1bih = (const float*)d_in[20];
  const float* c1bhh = (const float*)d_in[21];
  const float* c2Wih = (const float*)d_in[22];
  const float* c2Whh = (const float*)d_in[23];
  const float* c2bih = (const float*)d_in[24];
  const float* c2bhh = (const float*)d_in[25];
  const float* Wp = (const float*)d_in[26];
  const float* bp = (const float*)d_in[27];

  char* w = (char*)d_ws;
  size_t off = 0;
  auto alloc = [&](size_t bytes) { void* p = w + off; off = (off + bytes + 255) & ~(size_t)255; return p; };
  int* cptr = (int*)alloc(101 * 4);
  int* csrc = (int*)alloc(2000 * 4);
  float* cnorm = (float*)alloc(2000 * 4);
  float* XS = (float*)alloc((size_t)1024 * 3200 * 4);
  float* G0 = (float*)alloc((size_t)1024 * 2048 * 4);
  unsigned* W0p = (unsigned*)alloc((size_t)2048 * 256 * 4);
  unsigned* W1p = (unsigned*)alloc((size_t)2048 * 512 * 4);
  unsigned* c1Wih2 = (unsigned*)alloc((size_t)2048 * 1600 * 4);
  unsigned* c1Whh2 = (unsigned*)alloc((size_t)2048 * 256 * 4);
  unsigned* c2W2 = (unsigned*)alloc((size_t)2048 * 512 * 4);
  float* hs0 = (float*)alloc((size_t)64 * 16 * 512 * 4);
  float* h1ex = (float*)alloc((size_t)2 * 16 * 512 * 4);
  unsigned* h1pk = (unsigned*)alloc((size_t)2 * 16 * 256 * 4);
  unsigned* h2pk = (unsigned*)alloc((size_t)2 * 16 * 256 * 4);
  float* h2f = (float*)alloc((size_t)2 * 16 * 512 * 4);
  unsigned* flagzone = (unsigned*)alloc((128 + 128 + 256 + 16) * 4);
  unsigned* F0 = flagzone;
  unsigned* F1 = flagzone + 128;
  unsigned* bflags = flagzone + 256;
  unsigned* gen = flagzone + 512;

  hipMemsetAsync(flagzone, 0, (128 + 128 + 256 + 16) * 4, stream);

  setup_kernel<<<1, 256, 0, stream>>>(ei, ew, cptr, csrc, cnorm);
  pack_rows<<<(2048 * 256 + 255) / 256, 256, 0, stream>>>(Whh0, nullptr, 512, 0, 2048, W0p);
  pack_rows<<<(2048 * 512 + 255) / 256, 256, 0, stream>>>(Wih1, Whh1, 512, 512, 2048, W1p);
  pack_rows<<<(int)(((size_t)2048 * 1600 + 255) / 256), 256, 0, stream>>>(c1Wih, nullptr, 3200, 0, 2048, c1Wih2);
  pack_rows<<<(2048 * 256 + 255) / 256, 256, 0, stream>>>(c1Whh, nullptr, 512, 0, 2048, c1Whh2);
  pack_rows<<<(2048 * 512 + 255) / 256, 256, 0, stream>>>(c2Wih, c2Whh, 512, 512, 2048, c2W2);
  xs_kernel<<<400, 256, 0, stream>>>(window, cptr, csrc, cnorm, tgw, tgv, tgb, Wemb, XS);
  g0_gemm<<<dim3(32, 16), 256, 0, stream>>>(XS, Wih0, bih0, bhh0, G0);

  ScanArgs S;
  S.G0 = G0; S.W0p = W0p; S.W1p = W1p;
  S.bih1 = bih1; S.bhh1 = bhh1;
  S.hs0 = hs0; S.h1ex = h1ex;
  S.F0 = F0; S.F1 = F1;
  void* sp[] = { &S };
  hipLaunchCooperativeKernel(scan_kernel, dim3(256), dim3(512), sp, 0, stream);

  DecArgs D;
  D.c1Wih2 = c1Wih2; D.c1Whh2 = c1Whh2; D.c1bih = c1bih; D.c1bhh = c1bhh;
  D.c2W2 = c2W2; D.c2bih = c2bih; D.c2bhh = c2bhh;
  D.Wp = Wp; D.bp = bp; D.gw = gw; D.gv = gv; D.gb = gb; D.Wemb = Wemb;
  D.cptr = cptr; D.csrc = csrc; D.cnorm = cnorm;
  D.hs0 = hs0; D.h1ex = h1ex;
  D.h1pk = h1pk; D.h2pk = h2pk; D.h2f = h2f;
  D.bflags = bflags; D.gen = gen;
  D.out = (float*)d_out;
  void* dp[] = { &D };
  hipLaunchCooperativeKernel(dec_kernel, dim3(256), dim3(512), dp, 35520 * 4, stream);
}

// Round 9
// 2265.563 us; speedup vs baseline: 1.1595x; 1.1595x over previous
//
#include <hip/hip_runtime.h>
#include <math.h>

#define HZN 10
#define NBLK 256

__device__ __forceinline__ float sigm(float x) { return 1.f / (1.f + expf(-x)); }
__device__ __forceinline__ float gelu_f(float x) { return 0.5f * x * (1.f + erff(x * 0.70710678118654752f)); }

__device__ __forceinline__ float cLd(const float* p) {
  return __hip_atomic_load(p, __ATOMIC_RELAXED, __HIP_MEMORY_SCOPE_AGENT);
}
__device__ __forceinline__ void cSt(float* p, float v) {
  __hip_atomic_store(p, v, __ATOMIC_RELAXED, __HIP_MEMORY_SCOPE_AGENT);
}
__device__ __forceinline__ unsigned cLdU(const unsigned* p) {
  return __hip_atomic_load(p, __ATOMIC_RELAXED, __HIP_MEMORY_SCOPE_AGENT);
}
__device__ __forceinline__ void cStU(unsigned* p, unsigned v) {
  __hip_atomic_store(p, v, __ATOMIC_RELAXED, __HIP_MEMORY_SCOPE_AGENT);
}
__device__ __forceinline__ void vfence() {
  asm volatile("s_waitcnt vmcnt(0)" ::: "memory");
}

__device__ __forceinline__ float blo(unsigned u) { return __uint_as_float(u << 16); }
__device__ __forceinline__ float bhi(unsigned u) { return __uint_as_float(u & 0xffff0000u); }
__device__ __forceinline__ unsigned bfu(float x) {
  unsigned u = __float_as_uint(x);
  return (u + 0x7fffu + ((u >> 16) & 1u)) >> 16;
}
__device__ __forceinline__ unsigned packbf(float a, float b) {
  return bfu(a) | (bfu(b) << 16);
}

// detector barrier (rounds 2-5,7,8 proven)
__device__ __forceinline__ void gbar(unsigned* flags, unsigned* gen, int bid, int tid, unsigned& bgen) {
  ++bgen;
  vfence();
  __syncthreads();
  if (bid == 0) {
    if (tid > 0 && tid < NBLK) {
      while (cLdU(&flags[tid]) < bgen) __builtin_amdgcn_s_sleep(1);
    }
    __syncthreads();
    if (tid == 0) cStU(gen, bgen);
  } else {
    if (tid == 0) {
      cStU(&flags[bid], bgen);
      while (cLdU(gen) < bgen) __builtin_amdgcn_s_sleep(1);
    }
    __syncthreads();
  }
}

// ---------------------------------------------------------------- setup
__global__ void setup_kernel(const int* __restrict__ ei, const float* __restrict__ ew,
                             int* __restrict__ cptr, int* __restrict__ csrc, float* __restrict__ cnorm) {
  __shared__ float deg[100];
  __shared__ float dinv[100];
  __shared__ int cnt[100];
  __shared__ int pos[100];
  __shared__ int ptr[101];
  const int t = threadIdx.x;
  if (t < 100) { deg[t] = 0.f; cnt[t] = 0; }
  __syncthreads();
  for (int e = t; e < 2000; e += 256) {
    int c = ei[2000 + e];
    atomicAdd(&deg[c], ew[e]);
    atomicAdd(&cnt[c], 1);
  }
  __syncthreads();
  if (t < 100) dinv[t] = (deg[t] > 0.f) ? 1.f / sqrtf(fmaxf(deg[t], 1e-12f)) : 0.f;
  if (t == 0) {
    ptr[0] = 0;
    for (int n = 0; n < 100; ++n) ptr[n + 1] = ptr[n] + cnt[n];
  }
  __syncthreads();
  if (t < 100) pos[t] = ptr[t];
  if (t < 101) cptr[t] = ptr[t];
  __syncthreads();
  for (int e = t; e < 2000; e += 256) {
    int r = ei[e], c = ei[2000 + e];
    int p = atomicAdd(&pos[c], 1);
    csrc[p] = r;
    cnorm[p] = dinv[r] * ew[e] * dinv[c];
  }
}

// ------------------- weight packing: row-major bf16 pairs [rows][(Ka+Kb)/2]
__global__ void pack_rows(const float* __restrict__ A, const float* __restrict__ B,
                          int Ka, int Kb, int rows, unsigned* __restrict__ out) {
  int K2 = (Ka + Kb) >> 1;
  long idx = (long)blockIdx.x * 256 + threadIdx.x;
  if (idx >= (long)rows * K2) return;
  int row = idx / K2, q = idx - (long)row * K2;
  int j0 = 2 * q;
  float a = (j0 < Ka) ? A[(long)row * Ka + j0] : B[(long)row * Kb + (j0 - Ka)];
  float b = (j0 + 1 < Ka) ? A[(long)row * Ka + j0 + 1] : B[(long)row * Kb + (j0 + 1 - Ka)];
  out[idx] = packbf(a, b);
}

// ---------------------------------------------------------------- TGConv -> XS[T][B][3200]
__global__ void xs_kernel(const float* __restrict__ win,
                          const int* __restrict__ cptr, const int* __restrict__ csrc,
                          const float* __restrict__ cnorm,
                          const float* __restrict__ tgw, const float* __restrict__ tgv,
                          const float* __restrict__ tgb, const float* __restrict__ Wemb,
                          float* __restrict__ XS) {
  const int g = blockIdx.x * 256 + threadIdx.x;
  if (g >= 102400) return;
  const int n2 = g % 100;
  const int base = g - n2;
  float s = 0.f;
  const int p0 = cptr[n2], p1 = cptr[n2 + 1];
  for (int p = p0; p < p1; ++p) s += cnorm[p] * win[base + csrc[p]];
  const float x = win[g];
  const int t = g % 64;
  const int bb = g / 6400;
  const int n = (g / 64) % 100;
  float* dst = XS + (size_t)(t * 16 + bb) * 3200 + n * 32;
  for (int c = 0; c < 32; ++c) {
    float v = s * tgw[c] + x * tgv[c] + tgb[c];
    dst[c] = gelu_f(v) + Wemb[n * 32 + c];
  }
}

// ---------------------------------------------------------------- G0 = XS @ Wih0^T + biases
__global__ __launch_bounds__(256) void g0_gemm(const float* __restrict__ XS, const float* __restrict__ W,
                                               const float* __restrict__ b1, const float* __restrict__ b2,
                                               float* __restrict__ G0) {
  __shared__ float As[16][68];
  __shared__ float Bs[16][68];
  const int tid = threadIdx.x;
  const int m0 = blockIdx.y * 64, n0 = blockIdx.x * 64;
  const int tx = tid & 15, ty = tid >> 4;
  const int lr = tid >> 2, lk = (tid & 3) * 4;
  float acc[4][4] = {};
  for (int k0 = 0; k0 < 3200; k0 += 16) {
    float4 av = *(const float4*)&XS[(size_t)(m0 + lr) * 3200 + k0 + lk];
    float4 bv = *(const float4*)&W[(size_t)(n0 + lr) * 3200 + k0 + lk];
    As[lk + 0][lr] = av.x; As[lk + 1][lr] = av.y; As[lk + 2][lr] = av.z; As[lk + 3][lr] = av.w;
    Bs[lk + 0][lr] = bv.x; Bs[lk + 1][lr] = bv.y; Bs[lk + 2][lr] = bv.z; Bs[lk + 3][lr] = bv.w;
    __syncthreads();
#pragma unroll
    for (int kk = 0; kk < 16; ++kk) {
      float4 a = *(const float4*)&As[kk][ty * 4];
      float4 b = *(const float4*)&Bs[kk][tx * 4];
      acc[0][0] += a.x * b.x; acc[0][1] += a.x * b.y; acc[0][2] += a.x * b.z; acc[0][3] += a.x * b.w;
      acc[1][0] += a.y * b.x; acc[1][1] += a.y * b.y; acc[1][2] += a.y * b.z; acc[1][3] += a.y * b.w;
      acc[2][0] += a.z * b.x; acc[2][1] += a.z * b.y; acc[2][2] += a.z * b.z; acc[2][3] += a.z * b.w;
      acc[3][0] += a.w * b.x; acc[3][1] += a.w * b.y; acc[3][2] += a.w * b.z; acc[3][3] += a.w * b.w;
    }
    __syncthreads();
  }
#pragma unroll
  for (int i = 0; i < 4; ++i) {
    const int m = m0 + ty * 4 + i;
#pragma unroll
    for (int j = 0; j < 4; ++j) {
      const int nn = n0 + tx * 4 + j;
      G0[(size_t)m * 2048 + nn] = acc[i][j] + b1[nn] + b2[nn];
    }
  }
}

// ---------------------------------------------------------------- scan kernel (tightened)
struct ScanArgs {
  const float* G0;
  const unsigned* W0p;       // [2048][256]
  const unsigned* W1p;       // [2048][512]
  const float* bih1; const float* bhh1;
  float* hs0;     // [64][16][512]
  float* h1ex;    // [2][16][512]
  unsigned* F0;   // [16][8]
  unsigned* F1;   // [16][8]
};

__global__ __launch_bounds__(512, 1) void scan_kernel(ScanArgs A) {
  __shared__ float hl[1024];
  const int tid = threadIdx.x;
  const int bid = blockIdx.x;
  const int hf = tid & 1;
  const int u = tid >> 3;
  const int g = (tid >> 1) & 3;

  if (bid < 128) {
    const int b = bid >> 3, j = bid & 7;
    const int wrow = g * 512 + j * 64 + u;
    const uint4* wp = (const uint4*)A.W0p + (size_t)wrow * 64 + hf * 32;
    const float4* hl4 = (const float4*)hl + hf * 64;
    float c0r = 0.f;
    for (int t = 0; t < 64; ++t) {
      if (t > 0) {
        if (tid < 8) {
          while (cLdU(&A.F0[b * 8 + tid]) < (unsigned)t) {}
        }
        __syncthreads();
        hl[tid & 511] = cLd(&A.hs0[((size_t)(t - 1) * 16 + b) * 512 + (tid & 511)]);
        __syncthreads();
      }
      float acc = 0.f;
      if (t > 0) {
#pragma unroll 8
        for (int i = 0; i < 32; ++i) {
          uint4 w = wp[i];
          float4 ha = hl4[2 * i], hb2 = hl4[2 * i + 1];
          acc += blo(w.x) * ha.x + bhi(w.x) * ha.y + blo(w.y) * ha.z + bhi(w.y) * ha.w;
          acc += blo(w.z) * hb2.x + bhi(w.z) * hb2.y + blo(w.w) * hb2.z + bhi(w.w) * hb2.w;
        }
      }
      acc += __shfl_xor(acc, 1);
      float gF = __shfl_xor(acc, 2);
      float gG = __shfl_xor(acc, 4);
      float gO = __shfl_xor(acc, 6);
      if ((tid & 7) == 0) {
        const float* g0r = A.G0 + ((size_t)t * 16 + b) * 2048 + j * 64;
        float gi = acc + g0r[u];
        float gf = gF + g0r[512 + u];
        float gg = gG + g0r[1024 + u];
        float go = gO + g0r[1536 + u];
        c0r = sigm(gf) * c0r + sigm(gi) * tanhf(gg);
        float hn = sigm(go) * tanhf(c0r);
        cSt(&A.hs0[((size_t)t * 16 + b) * 512 + j * 64 + u], hn);
      }
      vfence();
      __syncthreads();
      if (tid == 0) cStU(&A.F0[b * 8 + j], t + 1);
    }
  } else {
    const int b = (bid - 128) >> 3, j = bid & 7;
    const int wrow = g * 512 + j * 64 + u;
    const uint4* wp = (const uint4*)A.W1p + (size_t)wrow * 128 + hf * 64;
    const float4* hl4 = (const float4*)hl + hf * 128;
    float c1s = 0.f;
    float bI = 0.f, bF = 0.f, bG = 0.f, bO = 0.f;
    if ((tid & 7) == 0) {
      int uu = j * 64 + u;
      bI = A.bih1[uu] + A.bhh1[uu];
      bF = A.bih1[512 + uu] + A.bhh1[512 + uu];
      bG = A.bih1[1024 + uu] + A.bhh1[1024 + uu];
      bO = A.bih1[1536 + uu] + A.bhh1[1536 + uu];
    }
    for (int t = 0; t < 64; ++t) {
      if (tid < 8) {
        while (cLdU(&A.F0[b * 8 + tid]) < (unsigned)(t + 1)) {}
      } else if (tid < 16) {
        if (t > 0) { while (cLdU(&A.F1[b * 8 + (tid - 8)]) < (unsigned)t) {} }
      }
      __syncthreads();
      hl[tid] = cLd(&A.hs0[((size_t)t * 16 + b) * 512 + tid]);
      hl[512 + tid] = (t > 0) ? cLd(&A.h1ex[(((t - 1) & 1) * 16 + b) * 512 + tid]) : 0.f;
      __syncthreads();
      float acc = 0.f;
#pragma unroll 8
      for (int i = 0; i < 64; ++i) {
        uint4 w = wp[i];
        float4 ha = hl4[2 * i], hb2 = hl4[2 * i + 1];
        acc += blo(w.x) * ha.x + bhi(w.x) * ha.y + blo(w.y) * ha.z + bhi(w.y) * ha.w;
        acc += blo(w.z) * hb2.x + bhi(w.z) * hb2.y + blo(w.w) * hb2.z + bhi(w.w) * hb2.w;
      }
      acc += __shfl_xor(acc, 1);
      float gF = __shfl_xor(acc, 2);
      float gG = __shfl_xor(acc, 4);
      float gO = __shfl_xor(acc, 6);
      if ((tid & 7) == 0) {
        float gi = acc + bI, gf = gF + bF, gg = gG + bG, go = gO + bO;
        c1s = sigm(gf) * c1s + sigm(gi) * tanhf(gg);
        float hn = sigm(go) * tanhf(c1s);
        cSt(&A.h1ex[((t & 1) * 16 + b) * 512 + j * 64 + u], hn);
      }
      vfence();
      __syncthreads();
      if (tid == 0) cStU(&A.F1[b * 8 + j], t + 1);
    }
  }
}

// ---------------------------------------------------------------- decoder kernel: 3 phases/step
struct DecArgs {
  const unsigned* c1Wih2;    // [2048][1600]
  const unsigned* c1Whh2;    // [2048][256]
  const float* c1bih; const float* c1bhh;
  const unsigned* c2W2;      // [2048][512]
  const float* c2bih; const float* c2bhh;
  const float* Wp; const float* bp;
  const float* gw; const float* gv; const float* gb;
  const float* Wemb;
  const int* cptr; const int* csrc; const float* cnorm;
  const float* hs0;
  const float* h1ex;
  float* xinE; float* xinO;   // [16][1600] each
  unsigned* h1pk; // [2][16][256]
  unsigned* h2pk; // [2][16][256]
  float* h2f;     // [2][16][512]
  unsigned* bflags; unsigned* gen;
  float* out;
};

// LDS layout (floats): xeven 12800 @0 | xodd @12800 | h1e @25600 | h1o @27648 | gatel @29696 (256)
#define DX_E 0
#define DX_O 12800
#define DH1E 25600
#define DH1O 27648
#define DGATE 29696
// PX scratch (overlays DX_E region): h2l@0(1024) predd@1024(512) dnrm@1536(512)
// s2l@2048(16) pl@2064(16) doffs@2080(16i) dcnts@2096(16i) dsrc@2112(512i) dli@2624(512i) dtot@3136

__global__ __launch_bounds__(512, 1) void dec_kernel(DecArgs A) {
  extern __shared__ float lds[];
  const int tid = threadIdx.x;
  const int bid = blockIdx.x;
  unsigned bgen = 0;

  const int u0 = bid * 2;
  float* xeven = lds + DX_E;
  float* xodd = lds + DX_O;
  float* h1e = lds + DH1E;
  float* h1o = lds + DH1O;
  float* gatel = lds + DGATE;

  const int nstart = (bid * 1600) >> 8;
  const int nend = ((bid + 1) * 1600) >> 8;
  const int ncnt = nend - nstart;       // 6 or 7
  const int nb0 = nstart / 100;

  float c1reg[2];
  float c2reg = 0.f;
  if (tid < 16) {
#pragma unroll
    for (int p = 0; p < 2; ++p) {
      int bl = tid >> 1, du = tid & 1;
      c1reg[p] = cLd(&A.hs0[((size_t)63 * 16 + p * 8 + bl) * 512 + u0 + du]);
    }
  }
  if (tid < 32) {
    int bl = tid >> 1, du = tid & 1;
    c2reg = cLd(&A.h1ex[(1 * 16 + bl) * 512 + u0 + du]);
  }

  for (int hz = 0; hz < HZN; ++hz) {
    const int cur = hz & 1, nxt = cur ^ 1;

    // ================= PX: pred dots + gather + xin (node-split, no redundancy) ==========
    {
      float* h2l = lds;            // 1024
      float* predd = lds + 1024;   // 512
      float* dnrm = lds + 1536;    // 512
      float* s2l = lds + 2048;     // 16
      float* pl = lds + 2064;      // 16
      int* doffs = (int*)(lds + 2080);
      int* dcnts = (int*)(lds + 2096);
      int* dsrc = (int*)(lds + 2112);
      int* dli = (int*)(lds + 2624);
      int* dtot = (int*)(lds + 3136);

      for (int k = 0; k < 2; ++k) {
        int i = k * 512 + tid;
        int bb = i >> 9, uu = i & 511;
        int bidx = nb0 + bb; if (bidx > 15) bidx = 15;
        float v = (hz == 0) ? cLd(&A.h1ex[(16 + bidx) * 512 + uu])
                            : cLd(&A.h2f[((size_t)cur * 16 + bidx) * 512 + uu]);
        h2l[i] = v;
      }
      if (tid < ncnt) {
        int gg = nstart + tid, n = gg % 100;
        dcnts[tid] = A.cptr[n + 1] - A.cptr[n] + 1;
      }
      __syncthreads();
      if (tid == 0) {
        int D = 0;
        for (int q = 0; q < ncnt; ++q) { doffs[q] = D; D += dcnts[q]; }
        *dtot = D;
      }
      __syncthreads();
      if (tid < ncnt) {
        int q = tid, gg = nstart + q, n = gg % 100;
        int o = doffs[q];
        dsrc[o] = n; dli[o] = q; dnrm[o] = 0.f;
        int p0 = A.cptr[n], p1 = A.cptr[n + 1];
        for (int p = p0; p < p1; ++p) {
          ++o;
          dsrc[o] = A.csrc[p]; dli[o] = q; dnrm[o] = A.cnorm[p];
        }
      }
      __syncthreads();
      const int D = *dtot;
      const int dslot = tid >> 4, ln = tid & 15;
      for (int base = 0; base < D; base += 32) {
        int dd = base + dslot;
        if (dd < D) {
          int q = dli[dd];
          int gg = nstart + q;
          int bloc = gg / 100 - nb0;
          int src = dsrc[dd];
          const float* hr = h2l + bloc * 512;
          const float* wr = A.Wp + src * 512;
          float a = 0.f;
#pragma unroll
          for (int kk = 0; kk < 32; ++kk) { int jx = kk * 16 + ln; a += hr[jx] * wr[jx]; }
          a += __shfl_xor(a, 1); a += __shfl_xor(a, 2); a += __shfl_xor(a, 4); a += __shfl_xor(a, 8);
          if (ln == 0) predd[dd] = a + A.bp[src];
        }
      }
      __syncthreads();
      if (tid < ncnt) {
        int q = tid;
        int o = doffs[q], c2n = dcnts[q];
        float s2 = 0.f;
        for (int p = 1; p < c2n; ++p) s2 += dnrm[o + p] * predd[o + p];
        s2l[q] = s2;
        float pv = predd[o];
        pl[q] = pv;
        A.out[(size_t)(nstart + q) * HZN + hz] = pv;
      }
      __syncthreads();
      if (tid < ncnt * 32) {
        int q = tid >> 5, c = tid & 31;
        int gg = nstart + q, b = gg / 100, n = gg % 100;
        float v = s2l[q] * A.gw[c] + pl[q] * A.gv[c] + A.gb[c];
        float xv = gelu_f(v) + A.Wemb[n * 32 + c];
        int pi = n * 16 + (c >> 1);
        if (c & 1) cSt(&A.xinO[(size_t)b * 1600 + pi], xv);
        else       cSt(&A.xinE[(size_t)b * 1600 + pi], xv);
      }
    }
    gbar(A.bflags, A.gen, bid, tid, bgen);

    // ================= C1: cell1 gates, 8 rows/block, 2 batch-passes ==========
#pragma unroll
    for (int p = 0; p < 2; ++p) {
      const int B0 = p * 8;
      for (int k = 0; k < 50; ++k) {
        int idx = k * 512 + tid;
        int half = idx / 12800;
        int r2 = idx - half * 12800;
        int bb = r2 / 1600, q = r2 - bb * 1600;
        float v = half ? cLd(&A.xinO[(size_t)(B0 + bb) * 1600 + q])
                       : cLd(&A.xinE[(size_t)(B0 + bb) * 1600 + q]);
        if (half) xodd[r2] = v; else xeven[r2] = v;
      }
      for (int k = 0; k < 4; ++k) {
        int i = k * 512 + tid;
        int bb = i >> 8, pp = i & 255;
        float x0, x1;
        if (hz == 0) {
          x0 = cLd(&A.hs0[((size_t)63 * 16 + B0 + bb) * 512 + 2 * pp]);
          x1 = cLd(&A.hs0[((size_t)63 * 16 + B0 + bb) * 512 + 2 * pp + 1]);
        } else {
          unsigned pk = cLdU(&A.h1pk[((size_t)cur * 16 + B0 + bb) * 256 + pp]);
          x0 = blo(pk); x1 = bhi(pk);
        }
        h1e[bb * 256 + pp] = x0;
        h1o[bb * 256 + pp] = x1;
      }
      __syncthreads();
      {
        float acc[8] = {};
        const int r_ = tid >> 6, ks = tid & 63;
        const int wrow = (r_ >> 1) * 512 + u0 + (r_ & 1);
        for (int jj = 0; jj < 25; ++jj) {
          int pi = jj * 64 + ks;
          unsigned w = A.c1Wih2[(size_t)wrow * 1600 + pi];
          float wl = blo(w), wh = bhi(w);
#pragma unroll
          for (int bb = 0; bb < 8; ++bb) {
            acc[bb] += wl * xeven[bb * 1600 + pi] + wh * xodd[bb * 1600 + pi];
          }
        }
        for (int jj = 0; jj < 4; ++jj) {
          int pi = jj * 64 + ks;
          unsigned w = A.c1Whh2[wrow * 256 + pi];
          float wl = blo(w), wh = bhi(w);
#pragma unroll
          for (int bb = 0; bb < 8; ++bb) {
            acc[bb] += wl * h1e[bb * 256 + pi] + wh * h1o[bb * 256 + pi];
          }
        }
#pragma unroll
        for (int bb = 0; bb < 8; ++bb) {
          float v = acc[bb];
          v += __shfl_xor(v, 32); v += __shfl_xor(v, 16); v += __shfl_xor(v, 8);
          v += __shfl_xor(v, 4); v += __shfl_xor(v, 2); v += __shfl_xor(v, 1);
          acc[bb] = v;
        }
        if (ks == 0) {
#pragma unroll
          for (int bb = 0; bb < 8; ++bb) gatel[r_ * 8 + bb] = acc[bb];
        }
      }
      __syncthreads();
      if (tid < 16) {
        int bl = tid >> 1, du = tid & 1;
        int uu = u0 + du;
        float gi = gatel[(0 + du) * 8 + bl] + A.c1bih[uu] + A.c1bhh[uu];
        float gf = gatel[(2 + du) * 8 + bl] + A.c1bih[512 + uu] + A.c1bhh[512 + uu];
        float gg = gatel[(4 + du) * 8 + bl] + A.c1bih[1024 + uu] + A.c1bhh[1024 + uu];
        float go = gatel[(6 + du) * 8 + bl] + A.c1bih[1536 + uu] + A.c1bhh[1536 + uu];
        float cn = sigm(gf) * c1reg[p] + sigm(gi) * tanhf(gg);
        float hn = sigm(go) * tanhf(cn);
        c1reg[p] = cn;
        float ho = __shfl(hn, tid ^ 1);
        if (du == 0) cStU(&A.h1pk[((size_t)nxt * 16 + B0 + bl) * 256 + bid], packbf(hn, ho));
      }
      __syncthreads();
    }
    gbar(A.bflags, A.gen, bid, tid, bgen);

    // ================= C2: cell2 ==========
    {
      unsigned* h1b = (unsigned*)lds;         // [16][256]
      unsigned* h2b = (unsigned*)lds + 4096;  // [16][256]
      for (int k = 0; k < 8; ++k) {
        int i = k * 512 + tid;
        int bb = i >> 8, pp = i & 255;
        h1b[i] = cLdU(&A.h1pk[((size_t)nxt * 16 + bb) * 256 + pp]);
        unsigned v2;
        if (hz == 0) {
          float x0 = cLd(&A.h1ex[(16 + bb) * 512 + 2 * pp]);
          float x1 = cLd(&A.h1ex[(16 + bb) * 512 + 2 * pp + 1]);
          v2 = packbf(x0, x1);
        } else {
          v2 = cLdU(&A.h2pk[((size_t)cur * 16 + bb) * 256 + pp]);
        }
        h2b[i] = v2;
      }
      __syncthreads();
      float acc[16] = {};
      const int r_ = tid >> 6, ks = tid & 63;
      const int wrow = (r_ >> 1) * 512 + u0 + (r_ & 1);
      for (int jj = 0; jj < 8; ++jj) {
        int pi = jj * 64 + ks;
        unsigned w = A.c2W2[wrow * 512 + pi];
        float wl = blo(w), wh = bhi(w);
        const unsigned* hsrc = (pi < 256) ? h1b : (h2b - 256);
#pragma unroll
        for (int bb = 0; bb < 16; ++bb) {
          unsigned hv = hsrc[bb * 256 + pi];
          acc[bb] += wl * blo(hv) + wh * bhi(hv);
        }
      }
#pragma unroll
      for (int bb = 0; bb < 16; ++bb) {
        float v = acc[bb];
        v += __shfl_xor(v, 32); v += __shfl_xor(v, 16); v += __shfl_xor(v, 8);
        v += __shfl_xor(v, 4); v += __shfl_xor(v, 2); v += __shfl_xor(v, 1);
        acc[bb] = v;
      }
      if (ks == 0) {
#pragma unroll
        for (int bb = 0; bb < 16; ++bb) gatel[r_ * 16 + bb] = acc[bb];
      }
      __syncthreads();
      if (tid < 32) {
        int bl = tid >> 1, du = tid & 1;
        int uu = u0 + du;
        float gi = gatel[(0 + du) * 16 + bl] + A.c2bih[uu] + A.c2bhh[uu];
        float gf = gatel[(2 + du) * 16 + bl] + A.c2bih[512 + uu] + A.c2bhh[512 + uu];
        float gg = gatel[(4 + du) * 16 + bl] + A.c2bih[1024 + uu] + A.c2bhh[1024 + uu];
        float go = gatel[(6 + du) * 16 + bl] + A.c2bih[1536 + uu] + A.c2bhh[1536 + uu];
        float cn = sigm(gf) * c2reg + sigm(gi) * tanhf(gg);
        float hn = sigm(go) * tanhf(cn);
        c2reg = cn;
        cSt(&A.h2f[((size_t)nxt * 16 + bl) * 512 + uu], hn);
        float ho = __shfl(hn, tid ^ 1);
        if (du == 0) cStU(&A.h2pk[((size_t)nxt * 16 + bl) * 256 + bid], packbf(hn, ho));
      }
      __syncthreads();
    }
    gbar(A.bflags, A.gen, bid, tid, bgen);
  }
}

// ---------------------------------------------------------------- launch
extern "C" void kernel_launch(void* const* d_in, const int* in_sizes, int n_in,
                              void* d_out, int out_size, void* d_ws, size_t ws_size,
                              hipStream_t stream) {
  (void)in_sizes; (void)n_in; (void)out_size; (void)ws_size;
  const float* window = (const float*)d_in[0];
  const int* ei = (const int*)d_in[1];
  const float* ew = (const float*)d_in[2];
  const float* Wemb = (const float*)d_in[3];
  const float* tgw = (const float*)d_in[4];
  const float* tgv = (const float*)d_in[5];
  const float* tgb = (const float*)d_in[6];
  const float* gw = (const float*)d_in[7];
  const float* gv = (const float*)d_in[8];
  const float* gb = (const float*)d_in[9];
  const float* Wih0 = (const float*)d_in[10];
  const float* Whh0 = (const float*)d_in[11];
  const float* bih0 = (const float*)d_in[12];
  const float* bhh0 = (const float*)d_in[13];
  const float* Wih1 = (const float*)d_in[14];
  const float* Whh1 = (const float*)d_in[15];
  const float* bih1 = (const float*)d_in[16];
  const float* bhh1 = (const float*)d_in[17];
  const float* c1Wih = (const float*)d_in[18];
  const float* c1Whh = (const float*)d_in[19];
  const float* c1bih = (const float*)d_in[20];
  const float* c1bhh = (const float*)d_in[21];
  const float* c2Wih = (const float*)d_in[22];
  const float* c2Whh = (const float*)d_in[23];
  const float* c2bih = (const float*)d_in[24];
  const float* c2bhh = (const float*)d_in[25];
  const float* Wp = (const float*)d_in[26];
  const float* bp = (const float*)d_in[27];

  char* w = (char*)d_ws;
  size_t off = 0;
  auto alloc = [&](size_t bytes) { void* p = w + off; off = (off + bytes + 255) & ~(size_t)255; return p; };
  int* cptr = (int*)alloc(101 * 4);
  int* csrc = (int*)alloc(2000 * 4);
  float* cnorm = (float*)alloc(2000 * 4);
  float* XS = (float*)alloc((size_t)1024 * 3200 * 4);
  float* G0 = (float*)alloc((size_t)1024 * 2048 * 4);
  unsigned* W0p = (unsigned*)alloc((size_t)2048 * 256 * 4);
  unsigned* W1p = (unsigned*)alloc((size_t)2048 * 512 * 4);
  unsigned* c1Wih2 = (unsigned*)alloc((size_t)2048 * 1600 * 4);
  unsigned* c1Whh2 = (unsigned*)alloc((size_t)2048 * 256 * 4);
  unsigned* c2W2 = (unsigned*)alloc((size_t)2048 * 512 * 4);
  float* hs0 = (float*)alloc((size_t)64 * 16 * 512 * 4);
  float* h1ex = (float*)alloc((size_t)2 * 16 * 512 * 4);
  float* xinE = (float*)alloc((size_t)16 * 1600 * 4);
  float* xinO = (float*)alloc((size_t)16 * 1600 * 4);
  unsigned* h1pk = (unsigned*)alloc((size_t)2 * 16 * 256 * 4);
  unsigned* h2pk = (unsigned*)alloc((size_t)2 * 16 * 256 * 4);
  float* h2f = (float*)alloc((size_t)2 * 16 * 512 * 4);
  unsigned* flagzone = (unsigned*)alloc((128 + 128 + 256 + 16) * 4);
  unsigned* F0 = flagzone;
  unsigned* F1 = flagzone + 128;
  unsigned* bflags = flagzone + 256;
  unsigned* gen = flagzone + 512;

  hipMemsetAsync(flagzone, 0, (128 + 128 + 256 + 16) * 4, stream);

  setup_kernel<<<1, 256, 0, stream>>>(ei, ew, cptr, csrc, cnorm);
  pack_rows<<<(2048 * 256 + 255) / 256, 256, 0, stream>>>(Whh0, nullptr, 512, 0, 2048, W0p);
  pack_rows<<<(2048 * 512 + 255) / 256, 256, 0, stream>>>(Wih1, Whh1, 512, 512, 2048, W1p);
  pack_rows<<<(int)(((size_t)2048 * 1600 + 255) / 256), 256, 0, stream>>>(c1Wih, nullptr, 3200, 0, 2048, c1Wih2);
  pack_rows<<<(2048 * 256 + 255) / 256, 256, 0, stream>>>(c1Whh, nullptr, 512, 0, 2048, c1Whh2);
  pack_rows<<<(2048 * 512 + 255) / 256, 256, 0, stream>>>(c2Wih, c2Whh, 512, 512, 2048, c2W2);
  xs_kernel<<<400, 256, 0, stream>>>(window, cptr, csrc, cnorm, tgw, tgv, tgb, Wemb, XS);
  g0_gemm<<<dim3(32, 16), 256, 0, stream>>>(XS, Wih0, bih0, bhh0, G0);

  ScanArgs S;
  S.G0 = G0; S.W0p = W0p; S.W1p = W1p;
  S.bih1 = bih1; S.bhh1 = bhh1;
  S.hs0 = hs0; S.h1ex = h1ex;
  S.F0 = F0; S.F1 = F1;
  void* sp[] = { &S };
  hipLaunchCooperativeKernel(scan_kernel, dim3(256), dim3(512), sp, 0, stream);

  DecArgs D;
  D.c1Wih2 = c1Wih2; D.c1Whh2 = c1Whh2; D.c1bih = c1bih; D.c1bhh = c1bhh;
  D.c2W2 = c2W2; D.c2bih = c2bih; D.c2bhh = c2bhh;
  D.Wp = Wp; D.bp = bp; D.gw = gw; D.gv = gv; D.gb = gb; D.Wemb = Wemb;
  D.cptr = cptr; D.csrc = csrc; D.cnorm = cnorm;
  D.hs0 = hs0; D.h1ex = h1ex;
  D.xinE = xinE; D.xinO = xinO;
  D.h1pk = h1pk; D.h2pk = h2pk; D.h2f = h2f;
  D.bflags = bflags; D.gen = gen;
  D.out = (float*)d_out;
  void* dp[] = { &D };
  hipLaunchCooperativeKernel(dec_kernel, dim3(256), dim3(512), dp, 29952 * 4, stream);
}

// Round 10
// 2186.126 us; speedup vs baseline: 1.2017x; 1.0363x over previous
//
#include <hip/hip_runtime.h>
#include <math.h>

#define HZN 10
#define NBLK 256

__device__ __forceinline__ float sigm(float x) { return 1.f / (1.f + expf(-x)); }
__device__ __forceinline__ float gelu_f(float x) { return 0.5f * x * (1.f + erff(x * 0.70710678118654752f)); }

__device__ __forceinline__ float cLd(const float* p) {
  return __hip_atomic_load(p, __ATOMIC_RELAXED, __HIP_MEMORY_SCOPE_AGENT);
}
__device__ __forceinline__ void cSt(float* p, float v) {
  __hip_atomic_store(p, v, __ATOMIC_RELAXED, __HIP_MEMORY_SCOPE_AGENT);
}
__device__ __forceinline__ unsigned cLdU(const unsigned* p) {
  return __hip_atomic_load(p, __ATOMIC_RELAXED, __HIP_MEMORY_SCOPE_AGENT);
}
__device__ __forceinline__ void cStU(unsigned* p, unsigned v) {
  __hip_atomic_store(p, v, __ATOMIC_RELAXED, __HIP_MEMORY_SCOPE_AGENT);
}
__device__ __forceinline__ void vfence() {
  asm volatile("s_waitcnt vmcnt(0)" ::: "memory");
}

__device__ __forceinline__ float blo(unsigned u) { return __uint_as_float(u << 16); }
__device__ __forceinline__ float bhi(unsigned u) { return __uint_as_float(u & 0xffff0000u); }
__device__ __forceinline__ unsigned bfu(float x) {
  unsigned u = __float_as_uint(x);
  return (u + 0x7fffu + ((u >> 16) & 1u)) >> 16;
}
__device__ __forceinline__ unsigned packbf(float a, float b) {
  return bfu(a) | (bfu(b) << 16);
}

// detector barrier (rounds 2-5,7-9 proven) -- decoder only
__device__ __forceinline__ void gbar(unsigned* flags, unsigned* gen, int bid, int tid, unsigned& bgen) {
  ++bgen;
  vfence();
  __syncthreads();
  if (bid == 0) {
    if (tid > 0 && tid < NBLK) {
      while (cLdU(&flags[tid]) < bgen) __builtin_amdgcn_s_sleep(1);
    }
    __syncthreads();
    if (tid == 0) cStU(gen, bgen);
  } else {
    if (tid == 0) {
      cStU(&flags[bid], bgen);
      while (cLdU(gen) < bgen) __builtin_amdgcn_s_sleep(1);
    }
    __syncthreads();
  }
}

// ---------------------------------------------------------------- setup
__global__ void setup_kernel(const int* __restrict__ ei, const float* __restrict__ ew,
                             int* __restrict__ cptr, int* __restrict__ csrc, float* __restrict__ cnorm) {
  __shared__ float deg[100];
  __shared__ float dinv[100];
  __shared__ int cnt[100];
  __shared__ int pos[100];
  __shared__ int ptr[101];
  const int t = threadIdx.x;
  if (t < 100) { deg[t] = 0.f; cnt[t] = 0; }
  __syncthreads();
  for (int e = t; e < 2000; e += 256) {
    int c = ei[2000 + e];
    atomicAdd(&deg[c], ew[e]);
    atomicAdd(&cnt[c], 1);
  }
  __syncthreads();
  if (t < 100) dinv[t] = (deg[t] > 0.f) ? 1.f / sqrtf(fmaxf(deg[t], 1e-12f)) : 0.f;
  if (t == 0) {
    ptr[0] = 0;
    for (int n = 0; n < 100; ++n) ptr[n + 1] = ptr[n] + cnt[n];
  }
  __syncthreads();
  if (t < 100) pos[t] = ptr[t];
  if (t < 101) cptr[t] = ptr[t];
  __syncthreads();
  for (int e = t; e < 2000; e += 256) {
    int r = ei[e], c = ei[2000 + e];
    int p = atomicAdd(&pos[c], 1);
    csrc[p] = r;
    cnorm[p] = dinv[r] * ew[e] * dinv[c];
  }
}

// ------------------- weight packing: row-major bf16 pairs [rows][(Ka+Kb)/2]
__global__ void pack_rows(const float* __restrict__ A, const float* __restrict__ B,
                          int Ka, int Kb, int rows, unsigned* __restrict__ out) {
  int K2 = (Ka + Kb) >> 1;
  long idx = (long)blockIdx.x * 256 + threadIdx.x;
  if (idx >= (long)rows * K2) return;
  int row = idx / K2, q = idx - (long)row * K2;
  int j0 = 2 * q;
  float a = (j0 < Ka) ? A[(long)row * Ka + j0] : B[(long)row * Kb + (j0 - Ka)];
  float b = (j0 + 1 < Ka) ? A[(long)row * Ka + j0 + 1] : B[(long)row * Kb + (j0 + 1 - Ka)];
  out[idx] = packbf(a, b);
}

// ---------------------------------------------------------------- TGConv -> XS[T][B][3200]
__global__ void xs_kernel(const float* __restrict__ win,
                          const int* __restrict__ cptr, const int* __restrict__ csrc,
                          const float* __restrict__ cnorm,
                          const float* __restrict__ tgw, const float* __restrict__ tgv,
                          const float* __restrict__ tgb, const float* __restrict__ Wemb,
                          float* __restrict__ XS) {
  const int g = blockIdx.x * 256 + threadIdx.x;
  if (g >= 102400) return;
  const int n2 = g % 100;
  const int base = g - n2;
  float s = 0.f;
  const int p0 = cptr[n2], p1 = cptr[n2 + 1];
  for (int p = p0; p < p1; ++p) s += cnorm[p] * win[base + csrc[p]];
  const float x = win[g];
  const int t = g % 64;
  const int bb = g / 6400;
  const int n = (g / 64) % 100;
  float* dst = XS + (size_t)(t * 16 + bb) * 3200 + n * 32;
  for (int c = 0; c < 32; ++c) {
    float v = s * tgw[c] + x * tgv[c] + tgb[c];
    dst[c] = gelu_f(v) + Wemb[n * 32 + c];
  }
}

// ---------------------------------------------------------------- G0 = XS @ Wih0^T + biases
__global__ __launch_bounds__(256) void g0_gemm(const float* __restrict__ XS, const float* __restrict__ W,
                                               const float* __restrict__ b1, const float* __restrict__ b2,
                                               float* __restrict__ G0) {
  __shared__ float As[16][68];
  __shared__ float Bs[16][68];
  const int tid = threadIdx.x;
  const int m0 = blockIdx.y * 64, n0 = blockIdx.x * 64;
  const int tx = tid & 15, ty = tid >> 4;
  const int lr = tid >> 2, lk = (tid & 3) * 4;
  float acc[4][4] = {};
  for (int k0 = 0; k0 < 3200; k0 += 16) {
    float4 av = *(const float4*)&XS[(size_t)(m0 + lr) * 3200 + k0 + lk];
    float4 bv = *(const float4*)&W[(size_t)(n0 + lr) * 3200 + k0 + lk];
    As[lk + 0][lr] = av.x; As[lk + 1][lr] = av.y; As[lk + 2][lr] = av.z; As[lk + 3][lr] = av.w;
    Bs[lk + 0][lr] = bv.x; Bs[lk + 1][lr] = bv.y; Bs[lk + 2][lr] = bv.z; Bs[lk + 3][lr] = bv.w;
    __syncthreads();
#pragma unroll
    for (int kk = 0; kk < 16; ++kk) {
      float4 a = *(const float4*)&As[kk][ty * 4];
      float4 b = *(const float4*)&Bs[kk][tx * 4];
      acc[0][0] += a.x * b.x; acc[0][1] += a.x * b.y; acc[0][2] += a.x * b.z; acc[0][3] += a.x * b.w;
      acc[1][0] += a.y * b.x; acc[1][1] += a.y * b.y; acc[1][2] += a.y * b.z; acc[1][3] += a.y * b.w;
      acc[2][0] += a.z * b.x; acc[2][1] += a.z * b.y; acc[2][2] += a.z * b.z; acc[2][3] += a.z * b.w;
      acc[3][0] += a.w * b.x; acc[3][1] += a.w * b.y; acc[3][2] += a.w * b.z; acc[3][3] += a.w * b.w;
    }
    __syncthreads();
  }
#pragma unroll
  for (int i = 0; i < 4; ++i) {
    const int m = m0 + ty * 4 + i;
#pragma unroll
    for (int j = 0; j < 4; ++j) {
      const int nn = n0 + tx * 4 + j;
      G0[(size_t)m * 2048 + nn] = acc[i][j] + b1[nn] + b2[nn];
    }
  }
}

// ---------------------------------------------------------------- scan kernel: tag-in-mantissa, zero flags/fences
// h word = (fp32 bits & 0xFFFFFF00) | tag ; tag = step+1 (1..64); buffers zeroed each launch.
struct ScanArgs {
  const float* G0;
  const unsigned* W0p;       // [2048][256]
  const unsigned* W1p;       // [2048][512]
  const float* bih1; const float* bhh1;
  unsigned* hs0u;    // [64][16][512] tagged
  unsigned* h1exu;   // [2][16][512] tagged
};

__global__ __launch_bounds__(512, 1) void scan_kernel(ScanArgs A) {
  __shared__ float hl[1024];
  const int tid = threadIdx.x;
  const int bid = blockIdx.x;
  const int hf = tid & 1;
  const int u = tid >> 3;
  const int g = (tid >> 1) & 3;

  if (bid < 128) {
    // layer-0: block (b,j) owns units j*64..+63 of batch b
    const int b = bid >> 3, j = bid & 7;
    const int wrow = g * 512 + j * 64 + u;
    const uint4* wp = (const uint4*)A.W0p + (size_t)wrow * 64 + hf * 32;
    const float4* hl4 = (const float4*)hl + hf * 64;
    float c0r = 0.f;
    for (int t = 0; t < 64; ++t) {
      if (t > 0) {
        const unsigned tag = (unsigned)t & 0xFFu;
        const unsigned* p = &A.hs0u[(size_t)(t - 1) * 8192 + b * 512 + (tid & 511)];
        unsigned uu = cLdU(p);
        while ((uu & 0xFFu) != tag) { __builtin_amdgcn_s_sleep(2); uu = cLdU(p); }
        __syncthreads();                       // prior-iter hl reads complete
        hl[tid & 511] = __uint_as_float(uu & 0xFFFFFF00u);
        __syncthreads();
      }
      float acc = 0.f;
      if (t > 0) {
#pragma unroll 8
        for (int i = 0; i < 32; ++i) {
          uint4 w = wp[i];
          float4 ha = hl4[2 * i], hb2 = hl4[2 * i + 1];
          acc += blo(w.x) * ha.x + bhi(w.x) * ha.y + blo(w.y) * ha.z + bhi(w.y) * ha.w;
          acc += blo(w.z) * hb2.x + bhi(w.z) * hb2.y + blo(w.w) * hb2.z + bhi(w.w) * hb2.w;
        }
      }
      acc += __shfl_xor(acc, 1);
      float gF = __shfl_xor(acc, 2);
      float gG = __shfl_xor(acc, 4);
      float gO = __shfl_xor(acc, 6);
      if ((tid & 7) == 0) {
        const float* g0r = A.G0 + ((size_t)t * 16 + b) * 2048 + j * 64;
        float gi = acc + g0r[u];
        float gf = gF + g0r[512 + u];
        float gg = gG + g0r[1024 + u];
        float go = gO + g0r[1536 + u];
        c0r = sigm(gf) * c0r + sigm(gi) * tanhf(gg);
        float hn = sigm(go) * tanhf(c0r);
        unsigned hw = (__float_as_uint(hn) & 0xFFFFFF00u) | ((unsigned)(t + 1) & 0xFFu);
        cStU(&A.hs0u[(size_t)t * 8192 + b * 512 + j * 64 + u], hw);   // fire-and-forget
      }
    }
  } else {
    // layer-1
    const int b = (bid - 128) >> 3, j = bid & 7;
    const int wrow = g * 512 + j * 64 + u;
    const uint4* wp = (const uint4*)A.W1p + (size_t)wrow * 128 + hf * 64;
    const float4* hl4 = (const float4*)hl + hf * 128;
    float c1s = 0.f;
    float bI = 0.f, bF = 0.f, bG = 0.f, bO = 0.f;
    if ((tid & 7) == 0) {
      int uu = j * 64 + u;
      bI = A.bih1[uu] + A.bhh1[uu];
      bF = A.bih1[512 + uu] + A.bhh1[512 + uu];
      bG = A.bih1[1024 + uu] + A.bhh1[1024 + uu];
      bO = A.bih1[1536 + uu] + A.bhh1[1536 + uu];
    }
    for (int t = 0; t < 64; ++t) {
      const unsigned tagA = (unsigned)(t + 1) & 0xFFu;
      const unsigned* pa = &A.hs0u[(size_t)t * 8192 + b * 512 + tid];
      unsigned ua = cLdU(pa);
      while ((ua & 0xFFu) != tagA) { __builtin_amdgcn_s_sleep(2); ua = cLdU(pa); }
      unsigned ub = 0u;
      if (t > 0) {
        const unsigned tagB = (unsigned)t & 0xFFu;
        const unsigned* pb = &A.h1exu[(size_t)((t - 1) & 1) * 8192 + b * 512 + tid];
        ub = cLdU(pb);
        while ((ub & 0xFFu) != tagB) { __builtin_amdgcn_s_sleep(2); ub = cLdU(pb); }
      }
      __syncthreads();
      hl[tid] = __uint_as_float(ua & 0xFFFFFF00u);
      hl[512 + tid] = (t > 0) ? __uint_as_float(ub & 0xFFFFFF00u) : 0.f;
      __syncthreads();
      float acc = 0.f;
#pragma unroll 8
      for (int i = 0; i < 64; ++i) {
        uint4 w = wp[i];
        float4 ha = hl4[2 * i], hb2 = hl4[2 * i + 1];
        acc += blo(w.x) * ha.x + bhi(w.x) * ha.y + blo(w.y) * ha.z + bhi(w.y) * ha.w;
        acc += blo(w.z) * hb2.x + bhi(w.z) * hb2.y + blo(w.w) * hb2.z + bhi(w.w) * hb2.w;
      }
      acc += __shfl_xor(acc, 1);
      float gF = __shfl_xor(acc, 2);
      float gG = __shfl_xor(acc, 4);
      float gO = __shfl_xor(acc, 6);
      if ((tid & 7) == 0) {
        float gi = acc + bI, gf = gF + bF, gg = gG + bG, go = gO + bO;
        c1s = sigm(gf) * c1s + sigm(gi) * tanhf(gg);
        float hn = sigm(go) * tanhf(c1s);
        unsigned hw = (__float_as_uint(hn) & 0xFFFFFF00u) | ((unsigned)(t + 1) & 0xFFu);
        cStU(&A.h1exu[(size_t)(t & 1) * 8192 + b * 512 + j * 64 + u], hw);
      }
    }
  }
}

// ---------------------------------------------------------------- decoder kernel (R9 verbatim, passed)
struct DecArgs {
  const unsigned* c1Wih2;    // [2048][1600]
  const unsigned* c1Whh2;    // [2048][256]
  const float* c1bih; const float* c1bhh;
  const unsigned* c2W2;      // [2048][512]
  const float* c2bih; const float* c2bhh;
  const float* Wp; const float* bp;
  const float* gw; const float* gv; const float* gb;
  const float* Wemb;
  const int* cptr; const int* csrc; const float* cnorm;
  const float* hs0;
  const float* h1ex;
  float* xinE; float* xinO;   // [16][1600] each
  unsigned* h1pk; // [2][16][256]
  unsigned* h2pk; // [2][16][256]
  float* h2f;     // [2][16][512]
  unsigned* bflags; unsigned* gen;
  float* out;
};

#define DX_E 0
#define DX_O 12800
#define DH1E 25600
#define DH1O 27648
#define DGATE 29696

__global__ __launch_bounds__(512, 1) void dec_kernel(DecArgs A) {
  extern __shared__ float lds[];
  const int tid = threadIdx.x;
  const int bid = blockIdx.x;
  unsigned bgen = 0;

  const int u0 = bid * 2;
  float* xeven = lds + DX_E;
  float* xodd = lds + DX_O;
  float* h1e = lds + DH1E;
  float* h1o = lds + DH1O;
  float* gatel = lds + DGATE;

  const int nstart = (bid * 1600) >> 8;
  const int nend = ((bid + 1) * 1600) >> 8;
  const int ncnt = nend - nstart;
  const int nb0 = nstart / 100;

  float c1reg[2];
  float c2reg = 0.f;
  if (tid < 16) {
#pragma unroll
    for (int p = 0; p < 2; ++p) {
      int bl = tid >> 1, du = tid & 1;
      c1reg[p] = cLd(&A.hs0[((size_t)63 * 16 + p * 8 + bl) * 512 + u0 + du]);
    }
  }
  if (tid < 32) {
    int bl = tid >> 1, du = tid & 1;
    c2reg = cLd(&A.h1ex[(1 * 16 + bl) * 512 + u0 + du]);
  }

  for (int hz = 0; hz < HZN; ++hz) {
    const int cur = hz & 1, nxt = cur ^ 1;

    // ========== PX: pred dots + gather + xin (node-split) ==========
    {
      float* h2l = lds;
      float* predd = lds + 1024;
      float* dnrm = lds + 1536;
      float* s2l = lds + 2048;
      float* pl = lds + 2064;
      int* doffs = (int*)(lds + 2080);
      int* dcnts = (int*)(lds + 2096);
      int* dsrc = (int*)(lds + 2112);
      int* dli = (int*)(lds + 2624);
      int* dtot = (int*)(lds + 3136);

      for (int k = 0; k < 2; ++k) {
        int i = k * 512 + tid;
        int bb = i >> 9, uu = i & 511;
        int bidx = nb0 + bb; if (bidx > 15) bidx = 15;
        float v = (hz == 0) ? cLd(&A.h1ex[(16 + bidx) * 512 + uu])
                            : cLd(&A.h2f[((size_t)cur * 16 + bidx) * 512 + uu]);
        h2l[i] = v;
      }
      if (tid < ncnt) {
        int gg = nstart + tid, n = gg % 100;
        dcnts[tid] = A.cptr[n + 1] - A.cptr[n] + 1;
      }
      __syncthreads();
      if (tid == 0) {
        int D = 0;
        for (int q = 0; q < ncnt; ++q) { doffs[q] = D; D += dcnts[q]; }
        *dtot = D;
      }
      __syncthreads();
      if (tid < ncnt) {
        int q = tid, gg = nstart + q, n = gg % 100;
        int o = doffs[q];
        dsrc[o] = n; dli[o] = q; dnrm[o] = 0.f;
        int p0 = A.cptr[n], p1 = A.cptr[n + 1];
        for (int p = p0; p < p1; ++p) {
          ++o;
          dsrc[o] = A.csrc[p]; dli[o] = q; dnrm[o] = A.cnorm[p];
        }
      }
      __syncthreads();
      const int D = *dtot;
      const int dslot = tid >> 4, ln = tid & 15;
      for (int base = 0; base < D; base += 32) {
        int dd = base + dslot;
        if (dd < D) {
          int q = dli[dd];
          int gg = nstart + q;
          int bloc = gg / 100 - nb0;
          int src = dsrc[dd];
          const float* hr = h2l + bloc * 512;
          const float* wr = A.Wp + src * 512;
          float a = 0.f;
#pragma unroll
          for (int kk = 0; kk < 32; ++kk) { int jx = kk * 16 + ln; a += hr[jx] * wr[jx]; }
          a += __shfl_xor(a, 1); a += __shfl_xor(a, 2); a += __shfl_xor(a, 4); a += __shfl_xor(a, 8);
          if (ln == 0) predd[dd] = a + A.bp[src];
        }
      }
      __syncthreads();
      if (tid < ncnt) {
        int q = tid;
        int o = doffs[q], c2n = dcnts[q];
        float s2 = 0.f;
        for (int p = 1; p < c2n; ++p) s2 += dnrm[o + p] * predd[o + p];
        s2l[q] = s2;
        float pv = predd[o];
        pl[q] = pv;
        A.out[(size_t)(nstart + q) * HZN + hz] = pv;
      }
      __syncthreads();
      if (tid < ncnt * 32) {
        int q = tid >> 5, c = tid & 31;
        int gg = nstart + q, b = gg / 100, n = gg % 100;
        float v = s2l[q] * A.gw[c] + pl[q] * A.gv[c] + A.gb[c];
        float xv = gelu_f(v) + A.Wemb[n * 32 + c];
        int pi = n * 16 + (c >> 1);
        if (c & 1) cSt(&A.xinO[(size_t)b * 1600 + pi], xv);
        else       cSt(&A.xinE[(size_t)b * 1600 + pi], xv);
      }
    }
    gbar(A.bflags, A.gen, bid, tid, bgen);

    // ========== C1 ==========
#pragma unroll
    for (int p = 0; p < 2; ++p) {
      const int B0 = p * 8;
      for (int k = 0; k < 50; ++k) {
        int idx = k * 512 + tid;
        int half = idx / 12800;
        int r2 = idx - half * 12800;
        int bb = r2 / 1600, q = r2 - bb * 1600;
        float v = half ? cLd(&A.xinO[(size_t)(B0 + bb) * 1600 + q])
                       : cLd(&A.xinE[(size_t)(B0 + bb) * 1600 + q]);
        if (half) xodd[r2] = v; else xeven[r2] = v;
      }
      for (int k = 0; k < 4; ++k) {
        int i = k * 512 + tid;
        int bb = i >> 8, pp = i & 255;
        float x0, x1;
        if (hz == 0) {
          x0 = cLd(&A.hs0[((size_t)63 * 16 + B0 + bb) * 512 + 2 * pp]);
          x1 = cLd(&A.hs0[((size_t)63 * 16 + B0 + bb) * 512 + 2 * pp + 1]);
        } else {
          unsigned pk = cLdU(&A.h1pk[((size_t)cur * 16 + B0 + bb) * 256 + pp]);
          x0 = blo(pk); x1 = bhi(pk);
        }
        h1e[bb * 256 + pp] = x0;
        h1o[bb * 256 + pp] = x1;
      }
      __syncthreads();
      {
        float acc[8] = {};
        const int r_ = tid >> 6, ks = tid & 63;
        const int wrow = (r_ >> 1) * 512 + u0 + (r_ & 1);
        for (int jj = 0; jj < 25; ++jj) {
          int pi = jj * 64 + ks;
          unsigned w = A.c1Wih2[(size_t)wrow * 1600 + pi];
          float wl = blo(w), wh = bhi(w);
#pragma unroll
          for (int bb = 0; bb < 8; ++bb) {
            acc[bb] += wl * xeven[bb * 1600 + pi] + wh * xodd[bb * 1600 + pi];
          }
        }
        for (int jj = 0; jj < 4; ++jj) {
          int pi = jj * 64 + ks;
          unsigned w = A.c1Whh2[wrow * 256 + pi];
          float wl = blo(w), wh = bhi(w);
#pragma unroll
          for (int bb = 0; bb < 8; ++bb) {
            acc[bb] += wl * h1e[bb * 256 + pi] + wh * h1o[bb * 256 + pi];
          }
        }
#pragma unroll
        for (int bb = 0; bb < 8; ++bb) {
          float v = acc[bb];
          v += __shfl_xor(v, 32); v += __shfl_xor(v, 16); v += __shfl_xor(v, 8);
          v += __shfl_xor(v, 4); v += __shfl_xor(v, 2); v += __shfl_xor(v, 1);
          acc[bb] = v;
        }
        if (ks == 0) {
#pragma unroll
          for (int bb = 0; bb < 8; ++bb) gatel[r_ * 8 + bb] = acc[bb];
        }
      }
      __syncthreads();
      if (tid < 16) {
        int bl = tid >> 1, du = tid & 1;
        int uu = u0 + du;
        float gi = gatel[(0 + du) * 8 + bl] + A.c1bih[uu] + A.c1bhh[uu];
        float gf = gatel[(2 + du) * 8 + bl] + A.c1bih[512 + uu] + A.c1bhh[512 + uu];
        float gg = gatel[(4 + du) * 8 + bl] + A.c1bih[1024 + uu] + A.c1bhh[1024 + uu];
        float go = gatel[(6 + du) * 8 + bl] + A.c1bih[1536 + uu] + A.c1bhh[1536 + uu];
        float cn = sigm(gf) * c1reg[p] + sigm(gi) * tanhf(gg);
        float hn = sigm(go) * tanhf(cn);
        c1reg[p] = cn;
        float ho = __shfl(hn, tid ^ 1);
        if (du == 0) cStU(&A.h1pk[((size_t)nxt * 16 + B0 + bl) * 256 + bid], packbf(hn, ho));
      }
      __syncthreads();
    }
    gbar(A.bflags, A.gen, bid, tid, bgen);

    // ========== C2 ==========
    {
      unsigned* h1b = (unsigned*)lds;
      unsigned* h2b = (unsigned*)lds + 4096;
      for (int k = 0; k < 8; ++k) {
        int i = k * 512 + tid;
        int bb = i >> 8, pp = i & 255;
        h1b[i] = cLdU(&A.h1pk[((size_t)nxt * 16 + bb) * 256 + pp]);
        unsigned v2;
        if (hz == 0) {
          float x0 = cLd(&A.h1ex[(16 + bb) * 512 + 2 * pp]);
          float x1 = cLd(&A.h1ex[(16 + bb) * 512 + 2 * pp + 1]);
          v2 = packbf(x0, x1);
        } else {
          v2 = cLdU(&A.h2pk[((size_t)cur * 16 + bb) * 256 + pp]);
        }
        h2b[i] = v2;
      }
      __syncthreads();
      float acc[16] = {};
      const int r_ = tid >> 6, ks = tid & 63;
      const int wrow = (r_ >> 1) * 512 + u0 + (r_ & 1);
      for (int jj = 0; jj < 8; ++jj) {
        int pi = jj * 64 + ks;
        unsigned w = A.c2W2[wrow * 512 + pi];
        float wl = blo(w), wh = bhi(w);
        const unsigned* hsrc = (pi < 256) ? h1b : (h2b - 256);
#pragma unroll
        for (int bb = 0; bb < 16; ++bb) {
          unsigned hv = hsrc[bb * 256 + pi];
          acc[bb] += wl * blo(hv) + wh * bhi(hv);
        }
      }
#pragma unroll
      for (int bb = 0; bb < 16; ++bb) {
        float v = acc[bb];
        v += __shfl_xor(v, 32); v += __shfl_xor(v, 16); v += __shfl_xor(v, 8);
        v += __shfl_xor(v, 4); v += __shfl_xor(v, 2); v += __shfl_xor(v, 1);
        acc[bb] = v;
      }
      if (ks == 0) {
#pragma unroll
        for (int bb = 0; bb < 16; ++bb) gatel[r_ * 16 + bb] = acc[bb];
      }
      __syncthreads();
      if (tid < 32) {
        int bl = tid >> 1, du = tid & 1;
        int uu = u0 + du;
        float gi = gatel[(0 + du) * 16 + bl] + A.c2bih[uu] + A.c2bhh[uu];
        float gf = gatel[(2 + du) * 16 + bl] + A.c2bih[512 + uu] + A.c2bhh[512 + uu];
        float gg = gatel[(4 + du) * 16 + bl] + A.c2bih[1024 + uu] + A.c2bhh[1024 + uu];
        float go = gatel[(6 + du) * 16 + bl] + A.c2bih[1536 + uu] + A.c2bhh[1536 + uu];
        float cn = sigm(gf) * c2reg + sigm(gi) * tanhf(gg);
        float hn = sigm(go) * tanhf(cn);
        c2reg = cn;
        cSt(&A.h2f[((size_t)nxt * 16 + bl) * 512 + uu], hn);
        float ho = __shfl(hn, tid ^ 1);
        if (du == 0) cStU(&A.h2pk[((size_t)nxt * 16 + bl) * 256 + bid], packbf(hn, ho));
      }
      __syncthreads();
    }
    gbar(A.bflags, A.gen, bid, tid, bgen);
  }
}

// ---------------------------------------------------------------- launch
extern "C" void kernel_launch(void* const* d_in, const int* in_sizes, int n_in,
                              void* d_out, int out_size, void* d_ws, size_t ws_size,
                              hipStream_t stream) {
  (void)in_sizes; (void)n_in; (void)out_size; (void)ws_size;
  const float* window = (const float*)d_in[0];
  const int* ei = (const int*)d_in[1];
  const float* ew = (const float*)d_in[2];
  const float* Wemb = (const float*)d_in[3];
  const float* tgw = (const float*)d_in[4];
  const float* tgv = (const float*)d_in[5];
  const float* tgb = (const float*)d_in[6];
  const float* gw = (const float*)d_in[7];
  const float* gv = (const float*)d_in[8];
  const float* gb = (const float*)d_in[9];
  const float* Wih0 = (const float*)d_in[10];
  const float* Whh0 = (const float*)d_in[11];
  const float* bih0 = (const float*)d_in[12];
  const float* bhh0 = (const float*)d_in[13];
  const float* Wih1 = (const float*)d_in[14];
  const float* Whh1 = (const float*)d_in[15];
  const float* bih1 = (const float*)d_in[16];
  const float* bhh1 = (const float*)d_in[17];
  const float* c1Wih = (const float*)d_in[18];
  const float* c1Whh = (const float*)d_in[19];
  const float* c1bih = (const float*)d_in[20];
  const float* c1bhh = (const float*)d_in[21];
  const float* c2Wih = (const float*)d_in[22];
  const float* c2Whh = (const float*)d_in[23];
  const float* c2bih = (const float*)d_in[24];
  const float* c2bhh = (const float*)d_in[25];
  const float* Wp = (const float*)d_in[26];
  const float* bp = (const float*)d_in[27];

  char* w = (char*)d_ws;
  size_t off = 0;
  auto alloc = [&](size_t bytes) { void* p = w + off; off = (off + bytes + 255) & ~(size_t)255; return p; };
  int* cptr = (int*)alloc(101 * 4);
  int* csrc = (int*)alloc(2000 * 4);
  float* cnorm = (float*)alloc(2000 * 4);
  float* XS = (float*)alloc((size_t)1024 * 3200 * 4);
  float* G0 = (float*)alloc((size_t)1024 * 2048 * 4);
  unsigned* W0p = (unsigned*)alloc((size_t)2048 * 256 * 4);
  unsigned* W1p = (unsigned*)alloc((size_t)2048 * 512 * 4);
  unsigned* c1Wih2 = (unsigned*)alloc((size_t)2048 * 1600 * 4);
  unsigned* c1Whh2 = (unsigned*)alloc((size_t)2048 * 256 * 4);
  unsigned* c2W2 = (unsigned*)alloc((size_t)2048 * 512 * 4);
  float* hs0 = (float*)alloc((size_t)64 * 16 * 512 * 4);
  float* h1ex = (float*)alloc((size_t)2 * 16 * 512 * 4);
  float* xinE = (float*)alloc((size_t)16 * 1600 * 4);
  float* xinO = (float*)alloc((size_t)16 * 1600 * 4);
  unsigned* h1pk = (unsigned*)alloc((size_t)2 * 16 * 256 * 4);
  unsigned* h2pk = (unsigned*)alloc((size_t)2 * 16 * 256 * 4);
  float* h2f = (float*)alloc((size_t)2 * 16 * 512 * 4);
  unsigned* flagzone = (unsigned*)alloc((128 + 128 + 256 + 16) * 4);
  unsigned* bflags = flagzone + 256;
  unsigned* gen = flagzone + 512;

  hipMemsetAsync(flagzone, 0, (128 + 128 + 256 + 16) * 4, stream);
  hipMemsetAsync(hs0, 0, (size_t)64 * 16 * 512 * 4, stream);   // reset tags each launch
  hipMemsetAsync(h1ex, 0, (size_t)2 * 16 * 512 * 4, stream);

  setup_kernel<<<1, 256, 0, stream>>>(ei, ew, cptr, csrc, cnorm);
  pack_rows<<<(2048 * 256 + 255) / 256, 256, 0, stream>>>(Whh0, nullptr, 512, 0, 2048, W0p);
  pack_rows<<<(2048 * 512 + 255) / 256, 256, 0, stream>>>(Wih1, Whh1, 512, 512, 2048, W1p);
  pack_rows<<<(int)(((size_t)2048 * 1600 + 255) / 256), 256, 0, stream>>>(c1Wih, nullptr, 3200, 0, 2048, c1Wih2);
  pack_rows<<<(2048 * 256 + 255) / 256, 256, 0, stream>>>(c1Whh, nullptr, 512, 0, 2048, c1Whh2);
  pack_rows<<<(2048 * 512 + 255) / 256, 256, 0, stream>>>(c2Wih, c2Whh, 512, 512, 2048, c2W2);
  xs_kernel<<<400, 256, 0, stream>>>(window, cptr, csrc, cnorm, tgw, tgv, tgb, Wemb, XS);
  g0_gemm<<<dim3(32, 16), 256, 0, stream>>>(XS, Wih0, bih0, bhh0, G0);

  ScanArgs S;
  S.G0 = G0; S.W0p = W0p; S.W1p = W1p;
  S.bih1 = bih1; S.bhh1 = bhh1;
  S.hs0u = (unsigned*)hs0; S.h1exu = (unsigned*)h1ex;
  void* sp[] = { &S };
  hipLaunchCooperativeKernel(scan_kernel, dim3(256), dim3(512), sp, 0, stream);

  DecArgs D;
  D.c1Wih2 = c1Wih2; D.c1Whh2 = c1Whh2; D.c1bih = c1bih; D.c1bhh = c1bhh;
  D.c2W2 = c2W2; D.c2bih = c2bih; D.c2bhh = c2bhh;
  D.Wp = Wp; D.bp = bp; D.gw = gw; D.gv = gv; D.gb = gb; D.Wemb = Wemb;
  D.cptr = cptr; D.csrc = csrc; D.cnorm = cnorm;
  D.hs0 = hs0; D.h1ex = h1ex;
  D.xinE = xinE; D.xinO = xinO;
  D.h1pk = h1pk; D.h2pk = h2pk; D.h2f = h2f;
  D.bflags = bflags; D.gen = gen;
  D.out = (float*)d_out;
  void* dp[] = { &D };
  hipLaunchCooperativeKernel(dec_kernel, dim3(256), dim3(512), dp, 29952 * 4, stream);
}